// Round 7
// baseline (159.047 us; speedup 1.0000x reference)
//
#include <hip/hip_runtime.h>

// B=64, C=1024, HW=1024. x fp32 = 256 MiB = exactly L3 capacity.
// R5 proved: sliding-window pipeline cuts DRAM to ~265 MB (pool pass hits
// L3/MALL). R5's 344us came from ACQUIRE-in-poll-loop: agent-scope acquire
// = L2 invalidate (buffer_inv) per poll iteration x ~960 spinning blocks =
// memory-pipe meltdown. R7: identical structure, but
//   - polls are RELAXED (no cache maintenance) + s_sleep,
//   - ONE fence(ACQUIRE,"agent") after poll success, only where acquired
//     data is read (throttle gate: none -- x is read-only),
//   - score_done increment is RELEASE (small dirty wbl2), last-arriver
//     fences ACQUIRE once before merging peers' partials.
#define NB 64
#define NC 1024
#define NHW 1024
#define NCHUNK 16
#define CCH (NC / NCHUNK)     // 64 channels per block
#define WINDOW 32
#define NBLK (NB * NCHUNK)    // 1024 blocks

#define AGENT __HIP_MEMORY_SCOPE_AGENT

__device__ inline float wave_reduce_sum(float v) {
    #pragma unroll
    for (int off = 32; off; off >>= 1) v += __shfl_xor(v, off);
    return v;
}
__device__ inline float wave_reduce_max(float v) {
    #pragma unroll
    for (int off = 32; off; off >>= 1) v = fmaxf(v, __shfl_xor(v, off));
    return v;
}

// ctrl layout (ints): [0] claim ctr | [64..127] score_done[b] | [128..191] flag[b]
__global__ __launch_bounds__(256, 4) void fused_pipeline_kernel(
        const float* __restrict__ x, const float* __restrict__ w,
        float* __restrict__ partials, float* __restrict__ attn,
        int* __restrict__ ctrl, float* __restrict__ out) {
    __shared__ int s_vbid;
    __shared__ int s_last;
    __shared__ float redm[4], reds[4];

    const int tid  = threadIdx.x;
    const int wave = tid >> 6, lane = tid & 63;

    if (tid == 0)
        s_vbid = __hip_atomic_fetch_add(&ctrl[0], 1, __ATOMIC_RELAXED, AGENT);
    __syncthreads();
    const int vbid  = s_vbid;
    const int b     = vbid >> 4;
    const int chunk = vbid & 15;
    const int c0    = chunk * CCH;
    int* score_done = ctrl + 64;
    int* flag       = ctrl + 128;

    // ---- throttle gate: RELAXED poll only, NO fence (x is read-only;
    //      a stale read here just delays, never corrupts) ----
    if (b >= WINDOW) {
        if (tid == 0) {
            while (__hip_atomic_load(&flag[b - WINDOW], __ATOMIC_RELAXED, AGENT) == 0)
                __builtin_amdgcn_s_sleep(32);
        }
        __syncthreads();
    }

    // ---- score phase: partial scores from this 256 KiB slab (DRAM) ----
    const float* xb = x + ((size_t)(b * NC + c0)) * NHW + tid * 4;
    float4 ps = {0.f, 0.f, 0.f, 0.f};
    #pragma unroll 8
    for (int k = 0; k < CCH; ++k) {
        const float4 v = *reinterpret_cast<const float4*>(xb + (size_t)k * NHW);
        const float wk = w[c0 + k];          // wave-uniform -> scalar load
        ps.x += v.x * wk; ps.y += v.y * wk;
        ps.z += v.z * wk; ps.w += v.w * wk;
    }
    reinterpret_cast<float4*>(partials + (size_t)vbid * NHW)[tid] = ps;

    __syncthreads();   // all partial stores vmcnt-drained before the release
    if (tid == 0) {
        int prev = __hip_atomic_fetch_add(&score_done[b], 1, __ATOMIC_RELEASE, AGENT);
        s_last = (prev == NCHUNK - 1);
    }
    __syncthreads();

    if (s_last) {
        // one acquire to see the 15 peers' partials, then merge + softmax
        __builtin_amdgcn_fence(__ATOMIC_ACQUIRE, "agent");
        const float4* pb = reinterpret_cast<const float4*>(
            partials + (size_t)b * NCHUNK * NHW);
        float4 s = {0.f, 0.f, 0.f, 0.f};
        #pragma unroll
        for (int i = 0; i < NCHUNK; ++i) {
            const float4 p = pb[i * (NHW / 4) + tid];
            s.x += p.x; s.y += p.y; s.z += p.z; s.w += p.w;
        }
        float m = fmaxf(fmaxf(s.x, s.y), fmaxf(s.z, s.w));
        m = wave_reduce_max(m);
        if (lane == 0) redm[wave] = m;
        __syncthreads();
        m = fmaxf(fmaxf(redm[0], redm[1]), fmaxf(redm[2], redm[3]));
        float4 e;
        e.x = __expf(s.x - m); e.y = __expf(s.y - m);
        e.z = __expf(s.z - m); e.w = __expf(s.w - m);
        float z = e.x + e.y + e.z + e.w;
        z = wave_reduce_sum(z);
        if (lane == 0) reds[wave] = z;
        __syncthreads();
        const float inv = 1.0f / (reds[0] + reds[1] + reds[2] + reds[3]);
        e.x *= inv; e.y *= inv; e.z *= inv; e.w *= inv;
        reinterpret_cast<float4*>(attn + (size_t)b * NHW)[tid] = e;
        __syncthreads();   // attn stores drained before the release
        if (tid == 0)
            __hip_atomic_store(&flag[b], 1, __ATOMIC_RELEASE, AGENT);
    } else {
        // RELAXED poll; single acquire after success (we read attn next)
        if (tid == 0) {
            while (__hip_atomic_load(&flag[b], __ATOMIC_RELAXED, AGENT) == 0)
                __builtin_amdgcn_s_sleep(32);
        }
        __syncthreads();
        __builtin_amdgcn_fence(__ATOMIC_ACQUIRE, "agent");
    }

    // ---- pool phase: re-read slab (L3-hot), 16 channels per wave ----
    const float4* ar = reinterpret_cast<const float4*>(attn + (size_t)b * NHW);
    const float4 av0 = ar[4 * lane + 0];
    const float4 av1 = ar[4 * lane + 1];
    const float4 av2 = ar[4 * lane + 2];
    const float4 av3 = ar[4 * lane + 3];
    for (int cc = wave; cc < CCH; cc += 4) {
        const float4* xr = reinterpret_cast<const float4*>(
            x + ((size_t)(b * NC + c0 + cc)) * NHW);
        const float4 x0 = xr[4 * lane + 0];
        const float4 x1 = xr[4 * lane + 1];
        const float4 x2 = xr[4 * lane + 2];
        const float4 x3 = xr[4 * lane + 3];
        float acc = x0.x * av0.x + x0.y * av0.y + x0.z * av0.z + x0.w * av0.w
                  + x1.x * av1.x + x1.y * av1.y + x1.z * av1.z + x1.w * av1.w
                  + x2.x * av2.x + x2.y * av2.y + x2.z * av2.z + x2.w * av2.w
                  + x3.x * av3.x + x3.y * av3.y + x3.z * av3.z + x3.w * av3.w;
        acc = wave_reduce_sum(acc);
        if (lane == 0) out[b * NC + c0 + cc] = acc;
    }
}

extern "C" void kernel_launch(void* const* d_in, const int* in_sizes, int n_in,
                              void* d_out, int out_size, void* d_ws, size_t ws_size,
                              hipStream_t stream) {
    const float* x = (const float*)d_in[0];
    const float* w = (const float*)d_in[1];
    // d_in[2] (bias) irrelevant under softmax (shift-invariance).
    float* out      = (float*)d_out;
    float* partials = (float*)d_ws;                            // 4 MiB
    float* attn     = partials + (size_t)NB * NCHUNK * NHW;    // 256 KiB
    int*   ctrl     = (int*)(attn + (size_t)NB * NHW);         // 192 ints

    hipMemsetAsync(ctrl, 0, 192 * sizeof(int), stream);        // capture-legal
    fused_pipeline_kernel<<<NBLK, 256, 0, stream>>>(x, w, partials, attn,
                                                    ctrl, out);
}

// Round 8
// 100.220 us; speedup vs baseline: 1.5870x; 1.5870x over previous
//
#include <hip/hip_runtime.h>
#include <hip/hip_fp16.h>

// B=64, C=1024, HW=1024. x fp32 = 256 MiB. Two-pass floor = 512 MiB DRAM.
// R5-R7: intra-kernel sync wins traffic (FETCH 265MB) but loses execution
// (159-344us). R8: NO sync. Pass 1 streams x for scores AND writes an fp16
// shadow copy (128 MiB); pass 2 pools from the fp16 copy in REVERSE batch
// order -> freshly-written lines are MALL-resident (R4/R5 evidence: MALL
// retains ~128-256 MiB reuse distance). Worst case = baseline bytes (512
// MiB, write replaces a read); best case ~384 MiB.
// Precision: scores from fp32 (exact); pool from fp16 -> out err ~5e-5.
#define NB 64
#define NC 1024
#define NHW 1024
#define NCHUNK 16
#define CCH (NC / NCHUNK)   // 64 channels per K1 block

__device__ inline float wave_reduce_sum(float v) {
    #pragma unroll
    for (int off = 32; off; off >>= 1) v += __shfl_xor(v, off);
    return v;
}
__device__ inline float wave_reduce_max(float v) {
    #pragma unroll
    for (int off = 32; off; off >>= 1) v = fmaxf(v, __shfl_xor(v, off));
    return v;
}

// K1: partial scores + fp16 shadow copy. grid = NB*NCHUNK = 1024 blocks,
// 256 threads; thread owns hw = 4t..4t+3 of each of the chunk's 64 rows.
// Reads contiguous 256 KiB slab; writes 128 KiB fp16 + 4 KiB partials.
__global__ __launch_bounds__(256) void score_copy_kernel(
        const float* __restrict__ x, const float* __restrict__ w,
        __half* __restrict__ xh, float* __restrict__ partials) {
    const int tid   = threadIdx.x;
    const int b     = blockIdx.x >> 4;
    const int chunk = blockIdx.x & 15;
    const int c0    = chunk * CCH;
    const size_t base = ((size_t)(b * NC + c0)) * NHW + tid * 4;
    const float* xb = x + base;
    __half* hb      = xh + base;

    float4 ps = {0.f, 0.f, 0.f, 0.f};
    #pragma unroll 8
    for (int k = 0; k < CCH; ++k) {
        const float4 v = *reinterpret_cast<const float4*>(xb + (size_t)k * NHW);
        const float wk = w[c0 + k];              // wave-uniform -> scalar load
        ps.x += v.x * wk; ps.y += v.y * wk;
        ps.z += v.z * wk; ps.w += v.w * wk;
        __half2 h01 = __floats2half2_rn(v.x, v.y);
        __half2 h23 = __floats2half2_rn(v.z, v.w);
        *reinterpret_cast<__half2*>(hb + (size_t)k * NHW)     = h01;
        *reinterpret_cast<__half2*>(hb + (size_t)k * NHW + 2) = h23;
    }
    reinterpret_cast<float4*>(partials + (size_t)blockIdx.x * NHW)[tid] = ps;
}

// K2: merge 16 partials per batch + softmax -> attn. grid = NB, 256 thr.
// Bias dropped (softmax shift-invariance).
__global__ __launch_bounds__(256) void softmax_kernel(
        const float* __restrict__ partials, float* __restrict__ attn) {
    __shared__ float redm[4], reds[4];
    const int tid  = threadIdx.x;
    const int wave = tid >> 6, lane = tid & 63;
    const int b    = blockIdx.x;

    float4 s = {0.f, 0.f, 0.f, 0.f};
    #pragma unroll
    for (int i = 0; i < NCHUNK; ++i) {
        const float4 p = reinterpret_cast<const float4*>(
            partials + (size_t)(b * NCHUNK + i) * NHW)[tid];
        s.x += p.x; s.y += p.y; s.z += p.z; s.w += p.w;
    }
    float m = fmaxf(fmaxf(s.x, s.y), fmaxf(s.z, s.w));
    m = wave_reduce_max(m);
    if (lane == 0) redm[wave] = m;
    __syncthreads();
    m = fmaxf(fmaxf(redm[0], redm[1]), fmaxf(redm[2], redm[3]));
    float4 e;
    e.x = __expf(s.x - m); e.y = __expf(s.y - m);
    e.z = __expf(s.z - m); e.w = __expf(s.w - m);
    float z = e.x + e.y + e.z + e.w;
    z = wave_reduce_sum(z);
    if (lane == 0) reds[wave] = z;
    __syncthreads();
    const float inv = 1.0f / (reds[0] + reds[1] + reds[2] + reds[3]);
    e.x *= inv; e.y *= inv; e.z *= inv; e.w *= inv;
    reinterpret_cast<float4*>(attn + (size_t)b * NHW)[tid] = e;
}

// K3: out[b,c] = sum_hw xh[b,c,hw] * attn[b,hw], fp16 x-copy, REVERSED
// block order (newest-written xh first -> MALL hits). Wave per (b,c) row.
// grid = NB*NC/4 = 16384 blocks, 256 threads.
__global__ __launch_bounds__(256) void pool_half_kernel(
        const __half* __restrict__ xh, const float* __restrict__ attn,
        float* __restrict__ out) {
    const int rbid = (NB * NC / 4 - 1) - blockIdx.x;
    const int wave = threadIdx.x >> 6;
    const int lane = threadIdx.x & 63;
    const int out_idx = (rbid << 2) + wave;      // = b*NC + c
    const int b = out_idx >> 10;                 // NC = 1024

    // lane covers hw = 16*lane .. 16*lane+15 : two 16B half8 loads.
    const uint4* hr = reinterpret_cast<const uint4*>(xh + (size_t)out_idx * NHW);
    const float4* ar = reinterpret_cast<const float4*>(attn + (size_t)b * NHW);
    const uint4 ha = hr[2 * lane];
    const uint4 hbv = hr[2 * lane + 1];
    float4 a0 = ar[4 * lane + 0], a1 = ar[4 * lane + 1];
    float4 a2 = ar[4 * lane + 2], a3 = ar[4 * lane + 3];

    const __half2* h2a = reinterpret_cast<const __half2*>(&ha);
    const __half2* h2b = reinterpret_cast<const __half2*>(&hbv);
    float acc = 0.f;
    {
        float2 f0 = __half22float2(h2a[0]), f1 = __half22float2(h2a[1]);
        float2 f2 = __half22float2(h2a[2]), f3 = __half22float2(h2a[3]);
        acc += f0.x * a0.x + f0.y * a0.y + f1.x * a0.z + f1.y * a0.w;
        acc += f2.x * a1.x + f2.y * a1.y + f3.x * a1.z + f3.y * a1.w;
    }
    {
        float2 f0 = __half22float2(h2b[0]), f1 = __half22float2(h2b[1]);
        float2 f2 = __half22float2(h2b[2]), f3 = __half22float2(h2b[3]);
        acc += f0.x * a2.x + f0.y * a2.y + f1.x * a2.z + f1.y * a2.w;
        acc += f2.x * a3.x + f2.y * a3.y + f3.x * a3.z + f3.y * a3.w;
    }
    acc = wave_reduce_sum(acc);
    if (lane == 0) out[out_idx] = acc;
}

extern "C" void kernel_launch(void* const* d_in, const int* in_sizes, int n_in,
                              void* d_out, int out_size, void* d_ws, size_t ws_size,
                              hipStream_t stream) {
    const float* x = (const float*)d_in[0];
    const float* w = (const float*)d_in[1];
    // d_in[2] (bias) irrelevant under softmax (shift-invariance).
    float* out      = (float*)d_out;
    __half* xh      = (__half*)d_ws;                               // 128 MiB
    float* partials = (float*)(xh + (size_t)NB * NC * NHW);        // 4 MiB
    float* attn     = partials + (size_t)NB * NCHUNK * NHW;        // 256 KiB

    score_copy_kernel<<<NB * NCHUNK, 256, 0, stream>>>(x, w, xh, partials);
    softmax_kernel<<<NB, 256, 0, stream>>>(partials, attn);
    pool_half_kernel<<<(NB * NC) / 4, 256, 0, stream>>>(xh, attn, out);
}